// Round 12
// baseline (1041.760 us; speedup 1.0000x reference)
//
#include <hip/hip_runtime.h>
#include <hip/hip_cooperative_groups.h>

namespace cg = cooperative_groups;

#define NGRAPH 64

typedef _Float16 h4 __attribute__((ext_vector_type(4)));
typedef _Float16 h8 __attribute__((ext_vector_type(8)));
typedef float    f4 __attribute__((ext_vector_type(4)));
typedef float    f2 __attribute__((ext_vector_type(2)));

// ---- MFMA tile (no LDS): 64 rows/tile, 4 waves x 16 rows; B direct from global Wt ----
__device__ __forceinline__ void mfma_tile(const _Float16* __restrict__ A,
                                          const _Float16* __restrict__ Wt,
                                          const float* __restrict__ dinv,
                                          unsigned char* __restrict__ C,
                                          int N, int tile, int tid) {
  const int wv = tid >> 6, l = tid & 63;
  const int lm = l & 15, q = l >> 4;
  const int row0 = tile * 64 + wv * 16;

  const _Float16* Ap = &A[(size_t)(row0 + lm) * 128];
  h8 af[4];
#pragma unroll
  for (int kc = 0; kc < 4; ++kc)
    af[kc] = *(const h8*)&Ap[kc * 32 + q * 8];

  f4 acc[8];
#pragma unroll
  for (int ct = 0; ct < 8; ++ct) acc[ct] = (f4){0.0f, 0.0f, 0.0f, 0.0f};

#pragma unroll
  for (int ct = 0; ct < 8; ++ct) {
#pragma unroll
    for (int kc = 0; kc < 4; ++kc) {
      h8 bf = *(const h8*)&Wt[(size_t)(ct * 16 + lm) * 128 + kc * 32 + q * 8];
      acc[ct] = __builtin_amdgcn_mfma_f32_16x16x32_f16(af[kc], bf, acc[ct], 0, 0, 0);
    }
  }

#pragma unroll
  for (int r = 0; r < 4; ++r) {
    int row = row0 + q * 4 + r;
    if (row < N) {
      float dn = dinv[row];
      unsigned char* Cp = &C[(size_t)row * 128 + lm];
#pragma unroll
      for (int ct = 0; ct < 8; ++ct) {
        float v = acc[ct][r] * dn;
        unsigned int p = __builtin_amdgcn_cvt_pk_fp8_f32(v, v, 0, false);
        Cp[ct * 16] = (unsigned char)(p & 0xFF);
      }
    }
  }
}

// ---- gather phase (fp8 table -> fp16 h), grid-stride over node groups ----
__device__ __forceinline__ void gather_phase(const int* __restrict__ rowptr,
                                             const int* __restrict__ col,
                                             const unsigned char* __restrict__ xf8,
                                             const float* __restrict__ dinv,
                                             const float* __restrict__ b,
                                             _Float16* __restrict__ h,
                                             int N, int nb_gat, int bid, int nb, int tid) {
  const unsigned int* xw = (const unsigned int*)xf8;   // row stride 32 uints
  int sl = tid & 31;
  for (int c = bid; c < nb_gat; c += nb) {
    int node = c * 8 + (tid >> 5);
    if (node >= N) continue;
    int beg = rowptr[node], end = rowptr[node + 1];

    float a0 = 0.0f, a1 = 0.0f, a2 = 0.0f, a3 = 0.0f;
    int e = beg;
    for (; e + 3 < end; e += 4) {
      int s0 = col[e], s1 = col[e + 1], s2 = col[e + 2], s3 = col[e + 3];
      unsigned int w0 = xw[(size_t)s0 * 32 + sl];
      unsigned int w1 = xw[(size_t)s1 * 32 + sl];
      unsigned int w2 = xw[(size_t)s2 * 32 + sl];
      unsigned int w3 = xw[(size_t)s3 * 32 + sl];
      f2 l0 = __builtin_amdgcn_cvt_pk_f32_fp8((int)w0, false);
      f2 h0 = __builtin_amdgcn_cvt_pk_f32_fp8((int)w0, true);
      f2 l1 = __builtin_amdgcn_cvt_pk_f32_fp8((int)w1, false);
      f2 h1 = __builtin_amdgcn_cvt_pk_f32_fp8((int)w1, true);
      f2 l2 = __builtin_amdgcn_cvt_pk_f32_fp8((int)w2, false);
      f2 h2 = __builtin_amdgcn_cvt_pk_f32_fp8((int)w2, true);
      f2 l3 = __builtin_amdgcn_cvt_pk_f32_fp8((int)w3, false);
      f2 h3 = __builtin_amdgcn_cvt_pk_f32_fp8((int)w3, true);
      a0 += (l0[0] + l1[0]) + (l2[0] + l3[0]);
      a1 += (l0[1] + l1[1]) + (l2[1] + l3[1]);
      a2 += (h0[0] + h1[0]) + (h2[0] + h3[0]);
      a3 += (h0[1] + h1[1]) + (h2[1] + h3[1]);
    }
    for (; e < end; ++e) {
      unsigned int w0 = xw[(size_t)col[e] * 32 + sl];
      f2 l0 = __builtin_amdgcn_cvt_pk_f32_fp8((int)w0, false);
      f2 h0 = __builtin_amdgcn_cvt_pk_f32_fp8((int)w0, true);
      a0 += l0[0]; a1 += l0[1]; a2 += h0[0]; a3 += h0[1];
    }
    float dn = dinv[node];
    unsigned int wsf = xw[(size_t)node * 32 + sl];
    f2 sl0 = __builtin_amdgcn_cvt_pk_f32_fp8((int)wsf, false);
    f2 sh0 = __builtin_amdgcn_cvt_pk_f32_fp8((int)wsf, true);
    int cc = sl * 4;
    float4 bb = *(const float4*)&b[cc];
    h4 o;
    o[0] = (_Float16)fmaxf(fmaf(dn, a0 + sl0[0], bb.x), 0.0f);
    o[1] = (_Float16)fmaxf(fmaf(dn, a1 + sl0[1], bb.y), 0.0f);
    o[2] = (_Float16)fmaxf(fmaf(dn, a2 + sh0[0], bb.z), 0.0f);
    o[3] = (_Float16)fmaxf(fmaf(dn, a3 + sh0[1], bb.w), 0.0f);
    *(h4*)&h[(size_t)node * 128 + cc] = o;
  }
}

// ---- the mega kernel: all phases, grid.sync between ----
__global__ __launch_bounds__(256, 4) void k_mega(
    const float* __restrict__ x, const int* __restrict__ ei,
    const int* __restrict__ bat,
    const float* __restrict__ W1, const float* __restrict__ b1,
    const float* __restrict__ W2, const float* __restrict__ b2,
    const float* __restrict__ W3, const float* __restrict__ b3,
    const float* __restrict__ Wc, const float* __restrict__ bc,
    _Float16* __restrict__ XH, _Float16* __restrict__ Wt,
    int* __restrict__ deg, int* __restrict__ rowptr, int* __restrict__ bsum,
    float* __restrict__ dinv, int* __restrict__ col, int* __restrict__ rank,
    int* __restrict__ gstart,
    unsigned char* __restrict__ B1, _Float16* __restrict__ B2,
    float* __restrict__ out, int N, int E) {
  cg::grid_group grid = cg::this_grid();
  const int nb = gridDim.x;
  const int bid = blockIdx.x;
  const int tid = threadIdx.x;

  __shared__ int s[256];
  __shared__ float sp[8][128];

  const int nb_set = (N * 32 + 255) / 256;
  const int nb_N   = (N + 255) / 256;
  const int nb_E   = (E + 255) / 256;
  const int nb_gem = (N + 63) / 64;
  const int nb_gat = (N + 7) / 8;

  // ---- P1: setup (x->fp16, Wt transpose, deg=0, gbound) ----
  for (int c = bid; c < nb_set; c += nb) {
    int i = c * 256 + tid;
    if (i < N * 32) {
      float4 v = *(const float4*)&x[(size_t)i * 4];
      h4 o;
      o[0] = (_Float16)v.x; o[1] = (_Float16)v.y;
      o[2] = (_Float16)v.z; o[3] = (_Float16)v.w;
      *(h4*)&XH[(size_t)i * 4] = o;
    }
    if (i < 3 * 16384) {
      int l = i >> 14, j = i & 16383;
      int k = j >> 7, n = j & 127;
      const float* W = (l == 0) ? W1 : (l == 1) ? W2 : W3;
      Wt[l * 16384 + n * 128 + k] = (_Float16)W[k * 128 + n];
    }
    if (i < N) {
      deg[i] = 0;
      int b = bat[i];
      int prev = (i == 0) ? -1 : bat[i - 1];
      for (int g = prev + 1; g <= b; ++g) gstart[g] = i;
      if (i == N - 1)
        for (int g = b + 1; g <= NGRAPH; ++g) gstart[g] = N;
    }
  }
  grid.sync();

  // ---- P2: degree histogram + rank ----
  for (int c = bid; c < nb_E; c += nb) {
    int e = c * 256 + tid;
    if (e < E) rank[e] = atomicAdd(&deg[ei[E + e]], 1);
  }
  grid.sync();

  // ---- P3: block-local exclusive scan ----
  for (int c = bid; c < nb_N; c += nb) {
    int i = c * 256 + tid;
    int v = (i < N) ? deg[i] : 0;
    s[tid] = v;
    __syncthreads();
#pragma unroll
    for (int off = 1; off < 256; off <<= 1) {
      int t = (tid >= off) ? s[tid - off] : 0;
      __syncthreads();
      s[tid] += t;
      __syncthreads();
    }
    if (i < N) rowptr[i] = s[tid] - v;
    if (tid == 255) bsum[c] = s[255];
    __syncthreads();
  }
  grid.sync();

  // ---- P4: chunk offsets + dinv ----
  for (int c = bid; c < nb_N; c += nb) {
    int partial = 0;
    for (int j = tid; j < c; j += 256) partial += bsum[j];
    s[tid] = partial;
    __syncthreads();
#pragma unroll
    for (int off = 128; off > 0; off >>= 1) {
      if (tid < off) s[tid] += s[tid + off];
      __syncthreads();
    }
    int boff = s[0];
    __syncthreads();
    int i = c * 256 + tid;
    if (i < N) {
      rowptr[i] += boff;
      dinv[i] = rsqrtf((float)deg[i] + 1.0f);
    }
    if (i == 0) rowptr[N] = E;
  }
  grid.sync();

  // ---- P5: CSR fill (atomic-free) overlapped with mfma layer 1 ----
  {
    int total = nb_gem + nb_E;
    for (int c = bid; c < total; c += nb) {
      if (c < nb_gem) {
        mfma_tile(XH, Wt, dinv, B1, N, c, tid);
      } else {
        int e = (c - nb_gem) * 256 + tid;
        if (e < E) {
          int d = ei[E + e];
          col[rowptr[d] + rank[e]] = ei[e];
        }
      }
    }
  }
  grid.sync();

  // ---- P6: gather layer 1 ----
  gather_phase(rowptr, col, B1, dinv, b1, B2, N, nb_gat, bid, nb, tid);
  grid.sync();

  // ---- P7: mfma layer 2 ----
  for (int c = bid; c < nb_gem; c += nb) mfma_tile(B2, Wt + 16384, dinv, B1, N, c, tid);
  grid.sync();

  // ---- P8: gather layer 2 ----
  gather_phase(rowptr, col, B1, dinv, b2, B2, N, nb_gat, bid, nb, tid);
  grid.sync();

  // ---- P9: mfma layer 3 ----
  for (int c = bid; c < nb_gem; c += nb) mfma_tile(B2, Wt + 32768, dinv, B1, N, c, tid);
  grid.sync();

  // ---- P10: gather layer 3 ----
  gather_phase(rowptr, col, B1, dinv, b3, B2, N, nb_gat, bid, nb, tid);
  grid.sync();

  // ---- P11: pool + head, one block per graph ----
  for (int g = bid; g < NGRAPH; g += nb) {
    int beg = gstart[g], end = gstart[g + 1];
    int ty = tid >> 5;
    int q = (tid & 31) * 4;
    float4 acc; acc.x = acc.y = acc.z = acc.w = 0.0f;
    for (int r = beg + ty; r < end; r += 8) {
      h4 v = *(const h4*)&B2[(size_t)r * 128 + q];
      acc.x += (float)v[0]; acc.y += (float)v[1];
      acc.z += (float)v[2]; acc.w += (float)v[3];
    }
    *(float4*)&sp[ty][q] = acc;
    __syncthreads();
    if (tid < 32) {
      int qq = tid * 4;
      float4 t; t.x = t.y = t.z = t.w = 0.0f;
#pragma unroll
      for (int j = 0; j < 8; ++j) {
        float4 v = *(float4*)&sp[j][qq];
        t.x += v.x; t.y += v.y; t.z += v.z; t.w += v.w;
      }
      *(float4*)&sp[0][qq] = t;
    }
    __syncthreads();
    if (tid < 10) {
      float cntf = (float)(end - beg);
      float inv = 1.0f / fmaxf(cntf, 1.0f);
      float a = 0.0f;
      for (int hh = 0; hh < 128; ++hh)
        a = fmaf(sp[0][hh], Wc[hh * 10 + tid], a);
      out[g * 10 + tid] = a * inv + bc[tid];
    }
    __syncthreads();
  }
}

extern "C" void kernel_launch(void* const* d_in, const int* in_sizes, int n_in,
                              void* d_out, int out_size, void* d_ws, size_t ws_size,
                              hipStream_t stream) {
  const float* x   = (const float*)d_in[0];
  const int*   ei  = (const int*)d_in[1];
  const int*   bat = (const int*)d_in[2];
  const float* W1  = (const float*)d_in[3];
  const float* b1  = (const float*)d_in[4];
  const float* W2  = (const float*)d_in[5];
  const float* b2  = (const float*)d_in[6];
  const float* W3  = (const float*)d_in[7];
  const float* b3  = (const float*)d_in[8];
  const float* Wc  = (const float*)d_in[9];
  const float* bc  = (const float*)d_in[10];
  float* outp = (float*)d_out;

  int N = in_sizes[0] / 128;
  int E = in_sizes[1] / 2;
  const int NP = ((N + 63) / 64) * 64;           // padded rows for MFMA A-loads

  // workspace layout
  char* wsb = (char*)d_ws;
  int*   deg    = (int*)wsb;                      wsb += (size_t)N * 4;
  int*   rowptr = (int*)wsb;                      wsb += (size_t)(N + 1) * 4;
  int*   bsum   = (int*)wsb;                      wsb += 256 * 4;
  float* dinv   = (float*)wsb;                    wsb += (size_t)N * 4;
  int*   col    = (int*)wsb;                      wsb += (size_t)E * 4;
  int*   rank   = (int*)wsb;                      wsb += (size_t)E * 4;
  int*   gstart = (int*)wsb;                      wsb += (NGRAPH + 1) * 4;
  wsb = (char*)(((size_t)wsb + 255) & ~(size_t)255);
  _Float16* Wt  = (_Float16*)wsb;                 wsb += 3 * 16384 * 2;
  wsb = (char*)(((size_t)wsb + 255) & ~(size_t)255);
  _Float16* XH  = (_Float16*)wsb;                 wsb += (size_t)NP * 128 * 2;
  unsigned char* B1 = (unsigned char*)wsb;        wsb += (size_t)NP * 128;     // fp8 table
  wsb = (char*)(((size_t)wsb + 255) & ~(size_t)255);
  _Float16* B2  = (_Float16*)wsb;

  int maxb = 0;
  hipOccupancyMaxActiveBlocksPerMultiprocessor(&maxb, (const void*)k_mega, 256, 0);
  if (maxb < 1) maxb = 1;
  if (maxb > 8) maxb = 8;
  int nblk = maxb * 256;                         // 256 CUs

  void* args[] = {
    (void*)&x, (void*)&ei, (void*)&bat,
    (void*)&W1, (void*)&b1, (void*)&W2, (void*)&b2, (void*)&W3, (void*)&b3,
    (void*)&Wc, (void*)&bc,
    (void*)&XH, (void*)&Wt, (void*)&deg, (void*)&rowptr, (void*)&bsum,
    (void*)&dinv, (void*)&col, (void*)&rank, (void*)&gstart,
    (void*)&B1, (void*)&B2, (void*)&outp, (void*)&N, (void*)&E
  };
  hipLaunchCooperativeKernel((const void*)k_mega, dim3(nblk), dim3(256),
                             args, 0, stream);
}

// Round 13
// 273.280 us; speedup vs baseline: 3.8121x; 3.8121x over previous
//
#include <hip/hip_runtime.h>

#define NGRAPH 64
#define HDIM 128
#define POOL_RS 8

typedef _Float16 h4 __attribute__((ext_vector_type(4)));
typedef _Float16 h8 __attribute__((ext_vector_type(8)));
typedef float    f4 __attribute__((ext_vector_type(4)));
typedef float    f2 __attribute__((ext_vector_type(2)));

// ---- fused setup + histogram: blocks [0,nb_set) do setup; [nb_set,..) do hist ----
// deg must be zeroed before this kernel (hipMemsetAsync).
__global__ __launch_bounds__(256) void k_setup_hist(const float* __restrict__ x,
                                                    const int* __restrict__ bat,
                                                    const int* __restrict__ ei,
                                                    const float* __restrict__ W1,
                                                    const float* __restrict__ W2,
                                                    const float* __restrict__ W3,
                                                    _Float16* __restrict__ XH,
                                                    _Float16* __restrict__ Wt,
                                                    int* __restrict__ deg,
                                                    int* __restrict__ rank,
                                                    float* __restrict__ sums,
                                                    int* __restrict__ gstart,
                                                    int N, int E, int nb_set) {
  int c = blockIdx.x;
  if (c < nb_set) {
    int i = c * 256 + threadIdx.x;
    if (i < N * 32) {                       // x (fp32) -> XH (fp16), 4 elems/thread
      float4 v = *(const float4*)&x[(size_t)i * 4];
      h4 o;
      o[0] = (_Float16)v.x; o[1] = (_Float16)v.y;
      o[2] = (_Float16)v.z; o[3] = (_Float16)v.w;
      *(h4*)&XH[(size_t)i * 4] = o;
    }
    if (i < 3 * 16384) {                    // Wt[l][n][k] = fp16(W_l[k][n])
      int l = i >> 14, j = i & 16383;
      int k = j >> 7, n = j & 127;
      const float* W = (l == 0) ? W1 : (l == 1) ? W2 : W3;
      Wt[l * 16384 + n * 128 + k] = (_Float16)W[k * 128 + n];
    }
    if (i < N) {
      int b = bat[i];
      int prev = (i == 0) ? -1 : bat[i - 1];
      for (int g = prev + 1; g <= b; ++g) gstart[g] = i;
      if (i == N - 1)
        for (int g = b + 1; g <= NGRAPH; ++g) gstart[g] = N;
    }
    if (i < NGRAPH * HDIM) sums[i] = 0.0f;
  } else {
    int e = (c - nb_set) * 256 + threadIdx.x;
    if (e < E) rank[e] = atomicAdd(&deg[ei[E + e]], 1);
  }
}

// ---- scan pass 1: per-block exclusive scan of deg ----
__global__ __launch_bounds__(256) void k_scan1(const int* __restrict__ deg,
                                               int* __restrict__ rowptr,
                                               int* __restrict__ bsum, int N) {
  __shared__ int s[256];
  int tid = threadIdx.x;
  int i = blockIdx.x * 256 + tid;
  int v = (i < N) ? deg[i] : 0;
  s[tid] = v;
  __syncthreads();
#pragma unroll
  for (int off = 1; off < 256; off <<= 1) {
    int t = (tid >= off) ? s[tid - off] : 0;
    __syncthreads();
    s[tid] += t;
    __syncthreads();
  }
  if (i < N) rowptr[i] = s[tid] - v;       // block-local exclusive
  if (tid == 255) bsum[blockIdx.x] = s[255];
}

// ---- scan pass 2+3 fused: each block redundantly reduces bsum[0..b); dinv ----
__global__ __launch_bounds__(256) void k_scan23(const int* __restrict__ deg,
                                                int* __restrict__ rowptr,
                                                const int* __restrict__ bsum,
                                                float* __restrict__ dinv,
                                                int N, int E) {
  __shared__ int red[256];
  int b = blockIdx.x, t = threadIdx.x;
  int partial = 0;
  for (int j = t; j < b; j += 256) partial += bsum[j];
  red[t] = partial;
  __syncthreads();
#pragma unroll
  for (int off = 128; off > 0; off >>= 1) {
    if (t < off) red[t] += red[t + off];
    __syncthreads();
  }
  int boff = red[0];
  int i = b * 256 + t;
  if (i < N) {
    rowptr[i] += boff;
    dinv[i] = rsqrtf((float)deg[i] + 1.0f);
  }
  if (i == 0) rowptr[N] = E;
}

// ---- MFMA GEMM body: C[N,128](fp8 e4m3) = dinv[row]*(A(fp16) @ W) ----
__device__ __forceinline__ void mfma_body(const _Float16* __restrict__ A,
                                          const _Float16* __restrict__ Wt,
                                          const float* __restrict__ dinv,
                                          unsigned char* __restrict__ C, int N,
                                          int bid, int tid, _Float16* ws) {
  // stage 128 rows x 128 halves = 2048 16B-chunks; 16 chunks/row
#pragma unroll
  for (int i = 0; i < 8; ++i) {
    int c0 = tid + i * 256;
    int r = c0 >> 4;
    int off = (c0 & 15) * 8;
    *(h8*)&ws[r * 136 + off] = *(const h8*)&Wt[r * 128 + off];
  }
  __syncthreads();

  const int wv = tid >> 6, l = tid & 63;
  const int lm = l & 15, q = l >> 4;
  const int rb = bid * 128 + wv * 32;

  h8 af[2][4];
#pragma unroll
  for (int mt = 0; mt < 2; ++mt) {
    const _Float16* Ap = &A[(size_t)(rb + mt * 16 + lm) * 128];
#pragma unroll
    for (int kc = 0; kc < 4; ++kc)
      af[mt][kc] = *(const h8*)&Ap[kc * 32 + q * 8];
  }

  f4 acc[2][8];
#pragma unroll
  for (int mt = 0; mt < 2; ++mt)
#pragma unroll
    for (int ct = 0; ct < 8; ++ct)
      acc[mt][ct] = (f4){0.0f, 0.0f, 0.0f, 0.0f};

#pragma unroll
  for (int ct = 0; ct < 8; ++ct) {
    h8 bf[4];
#pragma unroll
    for (int kc = 0; kc < 4; ++kc)
      bf[kc] = *(const h8*)&ws[(ct * 16 + lm) * 136 + kc * 32 + q * 8];
#pragma unroll
    for (int mt = 0; mt < 2; ++mt)
#pragma unroll
      for (int kc = 0; kc < 4; ++kc)
        acc[mt][ct] = __builtin_amdgcn_mfma_f32_16x16x32_f16(af[mt][kc], bf[kc],
                                                             acc[mt][ct], 0, 0, 0);
  }

#pragma unroll
  for (int mt = 0; mt < 2; ++mt) {
#pragma unroll
    for (int r = 0; r < 4; ++r) {
      int row = rb + mt * 16 + q * 4 + r;
      if (row < N) {
        float dn = dinv[row];
        unsigned char* Cp = &C[(size_t)row * 128 + lm];
#pragma unroll
        for (int ct = 0; ct < 8; ++ct) {
          float v = acc[mt][ct][r] * dn;
          unsigned int p = __builtin_amdgcn_cvt_pk_fp8_f32(v, v, 0, false);
          Cp[ct * 16] = (unsigned char)(p & 0xFF);
        }
      }
    }
  }
}

// ---- standalone MFMA GEMM (layers 2,3) ----
__global__ __launch_bounds__(256) void k_mfma(const _Float16* __restrict__ A,
                                              const _Float16* __restrict__ Wt,
                                              const float* __restrict__ dinv,
                                              unsigned char* __restrict__ C, int N) {
  __shared__ _Float16 ws[128 * 136];
  mfma_body(A, Wt, dinv, C, N, blockIdx.x, threadIdx.x, ws);
}

// ---- fused: blocks [0,nbg) do mfma layer-1; blocks [nbg,..) do atomic-free fill ----
__global__ __launch_bounds__(256) void k_fill_mfma(const _Float16* __restrict__ A,
                                                   const _Float16* __restrict__ Wt,
                                                   const float* __restrict__ dinv,
                                                   unsigned char* __restrict__ C,
                                                   const int* __restrict__ ei,
                                                   const int* __restrict__ rowptr,
                                                   const int* __restrict__ rank,
                                                   int* __restrict__ col,
                                                   int N, int E, int nbg) {
  __shared__ _Float16 ws[128 * 136];
  if ((int)blockIdx.x < nbg) {
    mfma_body(A, Wt, dinv, C, N, blockIdx.x, threadIdx.x, ws);
  } else {
    int e = (blockIdx.x - nbg) * 256 + threadIdx.x;
    if (e < E) {
      int d = ei[E + e];
      col[rowptr[d] + rank[e]] = ei[e];
    }
  }
}

// ---- fused gather (fp8 table -> fp16 h): h[n] = relu(dinv[n]*(xws[n]+sum xws[src])+b)
// half-wave (32 lanes) per node, lane owns 4 cols (4B fp8x4 loads); 8 nodes/block.
__global__ __launch_bounds__(256) void k_gather(const int* __restrict__ rowptr,
                                                const int* __restrict__ col,
                                                const unsigned char* __restrict__ xf8,
                                                const float* __restrict__ dinv,
                                                const float* __restrict__ b,
                                                _Float16* __restrict__ h, int N) {
  int node = blockIdx.x * 8 + (threadIdx.x >> 5);
  if (node >= N) return;
  int sl = threadIdx.x & 31;
  int beg = rowptr[node], end = rowptr[node + 1];
  const unsigned int* xw = (const unsigned int*)xf8;   // row stride 32 uints

  float a0 = 0.0f, a1 = 0.0f, a2 = 0.0f, a3 = 0.0f;
  int e = beg;
  for (; e + 3 < end; e += 4) {
    int s0 = col[e], s1 = col[e + 1], s2 = col[e + 2], s3 = col[e + 3];
    unsigned int w0 = xw[(size_t)s0 * 32 + sl];
    unsigned int w1 = xw[(size_t)s1 * 32 + sl];
    unsigned int w2 = xw[(size_t)s2 * 32 + sl];
    unsigned int w3 = xw[(size_t)s3 * 32 + sl];
    f2 l0 = __builtin_amdgcn_cvt_pk_f32_fp8((int)w0, false);
    f2 h0 = __builtin_amdgcn_cvt_pk_f32_fp8((int)w0, true);
    f2 l1 = __builtin_amdgcn_cvt_pk_f32_fp8((int)w1, false);
    f2 h1 = __builtin_amdgcn_cvt_pk_f32_fp8((int)w1, true);
    f2 l2 = __builtin_amdgcn_cvt_pk_f32_fp8((int)w2, false);
    f2 h2 = __builtin_amdgcn_cvt_pk_f32_fp8((int)w2, true);
    f2 l3 = __builtin_amdgcn_cvt_pk_f32_fp8((int)w3, false);
    f2 h3 = __builtin_amdgcn_cvt_pk_f32_fp8((int)w3, true);
    a0 += (l0[0] + l1[0]) + (l2[0] + l3[0]);
    a1 += (l0[1] + l1[1]) + (l2[1] + l3[1]);
    a2 += (h0[0] + h1[0]) + (h2[0] + h3[0]);
    a3 += (h0[1] + h1[1]) + (h2[1] + h3[1]);
  }
  for (; e < end; ++e) {
    unsigned int w0 = xw[(size_t)col[e] * 32 + sl];
    f2 l0 = __builtin_amdgcn_cvt_pk_f32_fp8((int)w0, false);
    f2 h0 = __builtin_amdgcn_cvt_pk_f32_fp8((int)w0, true);
    a0 += l0[0]; a1 += l0[1]; a2 += h0[0]; a3 += h0[1];
  }
  float dn = dinv[node];
  unsigned int wsf = xw[(size_t)node * 32 + sl];
  f2 sl0 = __builtin_amdgcn_cvt_pk_f32_fp8((int)wsf, false);
  f2 sh0 = __builtin_amdgcn_cvt_pk_f32_fp8((int)wsf, true);
  int c = sl * 4;
  float4 bb = *(const float4*)&b[c];
  h4 o;
  o[0] = (_Float16)fmaxf(fmaf(dn, a0 + sl0[0], bb.x), 0.0f);
  o[1] = (_Float16)fmaxf(fmaf(dn, a1 + sl0[1], bb.y), 0.0f);
  o[2] = (_Float16)fmaxf(fmaf(dn, a2 + sh0[0], bb.z), 0.0f);
  o[3] = (_Float16)fmaxf(fmaf(dn, a3 + sh0[1], bb.w), 0.0f);
  *(h4*)&h[(size_t)node * 128 + c] = o;
}

// ---- segmented mean-pool (fp16 h): grid (NGRAPH, POOL_RS) ----
__global__ __launch_bounds__(256) void k_pool(const _Float16* __restrict__ h,
                                              const int* __restrict__ gstart,
                                              float* __restrict__ sums) {
  int g = blockIdx.x;
  int rs = blockIdx.y;
  int beg = gstart[g], end = gstart[g + 1];
  int tid = threadIdx.x;
  int ty = tid >> 5;
  int q = (tid & 31) * 4;

  float4 acc; acc.x = acc.y = acc.z = acc.w = 0.0f;
  for (int r = beg + rs * 8 + ty; r < end; r += POOL_RS * 8) {
    h4 v = *(const h4*)&h[(size_t)r * 128 + q];
    acc.x += (float)v[0]; acc.y += (float)v[1];
    acc.z += (float)v[2]; acc.w += (float)v[3];
  }
  __shared__ float s[8][128];
  *(float4*)&s[ty][q] = acc;
  __syncthreads();
  if (tid < 32) {
    int qq = tid * 4;
    float4 t; t.x = t.y = t.z = t.w = 0.0f;
#pragma unroll
    for (int j = 0; j < 8; ++j) {
      float4 v = *(float4*)&s[j][qq];
      t.x += v.x; t.y += v.y; t.z += v.z; t.w += v.w;
    }
    float* base = &sums[g * 128 + qq];
    unsafeAtomicAdd(base + 0, t.x);
    unsafeAtomicAdd(base + 1, t.y);
    unsafeAtomicAdd(base + 2, t.z);
    unsafeAtomicAdd(base + 3, t.w);
  }
}

// ---- head ----
__global__ __launch_bounds__(640) void k_head(const float* __restrict__ sums,
                                              const int* __restrict__ gstart,
                                              const float* __restrict__ Wc,
                                              const float* __restrict__ bc,
                                              float* __restrict__ out) {
  int t = threadIdx.x;
  int g = t / 10, c = t % 10;
  float cntf = (float)(gstart[g + 1] - gstart[g]);
  float inv = 1.0f / fmaxf(cntf, 1.0f);
  float acc = 0.0f;
  for (int h = 0; h < 128; ++h)
    acc = fmaf(sums[g * 128 + h], Wc[h * 10 + c], acc);
  out[t] = acc * inv + bc[c];
}

extern "C" void kernel_launch(void* const* d_in, const int* in_sizes, int n_in,
                              void* d_out, int out_size, void* d_ws, size_t ws_size,
                              hipStream_t stream) {
  const float* x   = (const float*)d_in[0];
  const int*   ei  = (const int*)d_in[1];
  const int*   bat = (const int*)d_in[2];
  const float* W1  = (const float*)d_in[3];
  const float* b1  = (const float*)d_in[4];
  const float* W2  = (const float*)d_in[5];
  const float* b2  = (const float*)d_in[6];
  const float* W3  = (const float*)d_in[7];
  const float* b3  = (const float*)d_in[8];
  const float* Wc  = (const float*)d_in[9];
  const float* bc  = (const float*)d_in[10];

  const int N = in_sizes[0] / 128;
  const int E = in_sizes[1] / 2;
  const int NP = ((N + 127) / 128) * 128;        // padded rows for MFMA A-loads

  // workspace layout
  char* wsb = (char*)d_ws;
  int*   deg    = (int*)wsb;                      wsb += (size_t)N * 4;
  int*   rowptr = (int*)wsb;                      wsb += (size_t)(N + 1) * 4;
  int*   bsum   = (int*)wsb;                      wsb += 256 * 4;
  float* dinv   = (float*)wsb;                    wsb += (size_t)N * 4;
  int*   col    = (int*)wsb;                      wsb += (size_t)E * 4;
  int*   rank   = (int*)wsb;                      wsb += (size_t)E * 4;
  float* sums   = (float*)wsb;                    wsb += NGRAPH * HDIM * 4;
  int*   gstart = (int*)wsb;                      wsb += (NGRAPH + 1) * 4;
  wsb = (char*)(((size_t)wsb + 255) & ~(size_t)255);
  _Float16* Wt  = (_Float16*)wsb;                 wsb += 3 * 16384 * 2;
  wsb = (char*)(((size_t)wsb + 255) & ~(size_t)255);
  _Float16* XH  = (_Float16*)wsb;                 wsb += (size_t)NP * 128 * 2;
  unsigned char* B1 = (unsigned char*)wsb;        wsb += (size_t)NP * 128;     // fp8 table
  wsb = (char*)(((size_t)wsb + 255) & ~(size_t)255);
  _Float16* B2  = (_Float16*)wsb;

  const int nb_set = (N * 32 + 255) / 256;
  const int nb_N   = (N + 255) / 256;
  const int nb_E   = (E + 255) / 256;
  const int nb_gem = (N + 127) / 128;
  const int nb_gat = (N + 7) / 8;

  hipMemsetAsync(deg, 0, (size_t)N * 4, stream);
  k_setup_hist<<<nb_set + nb_E, 256, 0, stream>>>(x, bat, ei, W1, W2, W3,
                                                  XH, Wt, deg, rank, sums, gstart,
                                                  N, E, nb_set);
  k_scan1<<<nb_N, 256, 0, stream>>>(deg, rowptr, bsum, N);
  k_scan23<<<nb_N, 256, 0, stream>>>(deg, rowptr, bsum, dinv, N, E);

  // layer 1 GEMM overlapped with atomic-free CSR fill
  k_fill_mfma<<<nb_gem + nb_E, 256, 0, stream>>>(XH, Wt, dinv, B1,
                                                 ei, rowptr, rank, col, N, E, nb_gem);
  k_gather<<<nb_gat, 256, 0, stream>>>(rowptr, col, B1, dinv, b1, B2, N);

  k_mfma<<<nb_gem, 256, 0, stream>>>(B2, Wt + 16384, dinv, B1, N);
  k_gather<<<nb_gat, 256, 0, stream>>>(rowptr, col, B1, dinv, b2, B2, N);

  k_mfma<<<nb_gem, 256, 0, stream>>>(B2, Wt + 32768, dinv, B1, N);
  k_gather<<<nb_gat, 256, 0, stream>>>(rowptr, col, B1, dinv, b3, B2, N);

  dim3 pgrid(NGRAPH, POOL_RS);
  k_pool<<<pgrid, 256, 0, stream>>>(B2, gstart, sums);
  k_head<<<1, 640, 0, stream>>>(sums, gstart, Wc, bc, (float*)d_out);
}

// Round 14
// 265.338 us; speedup vs baseline: 3.9262x; 1.0299x over previous
//
#include <hip/hip_runtime.h>

#define NGRAPH 64
#define HDIM 128
#define POOL_RS 8

typedef _Float16 h4 __attribute__((ext_vector_type(4)));
typedef _Float16 h8 __attribute__((ext_vector_type(8)));
typedef float    f4 __attribute__((ext_vector_type(4)));
typedef float    f2 __attribute__((ext_vector_type(2)));

// ---- fused setup + histogram: blocks [0,nb_set) do setup; [nb_set,..) do hist ----
// deg must be zeroed before this kernel (hipMemsetAsync).
__global__ __launch_bounds__(256) void k_setup_hist(const int* __restrict__ bat,
                                                    const int* __restrict__ ei,
                                                    const float* __restrict__ W1,
                                                    const float* __restrict__ W2,
                                                    const float* __restrict__ W3,
                                                    _Float16* __restrict__ Wt,
                                                    int* __restrict__ deg,
                                                    int* __restrict__ rank,
                                                    float* __restrict__ sums,
                                                    int* __restrict__ gstart,
                                                    int N, int E, int nb_set) {
  int c = blockIdx.x;
  if (c < nb_set) {
    int i = c * 256 + threadIdx.x;
    if (i < 3 * 16384) {                    // Wt[l][n][k] = fp16(W_l[k][n])
      int l = i >> 14, j = i & 16383;
      int k = j >> 7, n = j & 127;
      const float* W = (l == 0) ? W1 : (l == 1) ? W2 : W3;
      Wt[l * 16384 + n * 128 + k] = (_Float16)W[k * 128 + n];
    }
    if (i < N) {
      int b = bat[i];
      int prev = (i == 0) ? -1 : bat[i - 1];
      for (int g = prev + 1; g <= b; ++g) gstart[g] = i;
      if (i == N - 1)
        for (int g = b + 1; g <= NGRAPH; ++g) gstart[g] = N;
    }
    if (i < NGRAPH * HDIM) sums[i] = 0.0f;
  } else {
    int e = (c - nb_set) * 256 + threadIdx.x;
    if (e < E) rank[e] = atomicAdd(&deg[ei[E + e]], 1);
  }
}

// ---- scan pass 1: per-block exclusive scan of deg ----
__global__ __launch_bounds__(256) void k_scan1(const int* __restrict__ deg,
                                               int* __restrict__ rowptr,
                                               int* __restrict__ bsum, int N) {
  __shared__ int s[256];
  int tid = threadIdx.x;
  int i = blockIdx.x * 256 + tid;
  int v = (i < N) ? deg[i] : 0;
  s[tid] = v;
  __syncthreads();
#pragma unroll
  for (int off = 1; off < 256; off <<= 1) {
    int t = (tid >= off) ? s[tid - off] : 0;
    __syncthreads();
    s[tid] += t;
    __syncthreads();
  }
  if (i < N) rowptr[i] = s[tid] - v;       // block-local exclusive
  if (tid == 255) bsum[blockIdx.x] = s[255];
}

// ---- scan pass 2+3 fused: each block redundantly reduces bsum[0..b); dinv ----
__global__ __launch_bounds__(256) void k_scan23(const int* __restrict__ deg,
                                                int* __restrict__ rowptr,
                                                const int* __restrict__ bsum,
                                                float* __restrict__ dinv,
                                                int N, int E) {
  __shared__ int red[256];
  int b = blockIdx.x, t = threadIdx.x;
  int partial = 0;
  for (int j = t; j < b; j += 256) partial += bsum[j];
  red[t] = partial;
  __syncthreads();
#pragma unroll
  for (int off = 128; off > 0; off >>= 1) {
    if (t < off) red[t] += red[t + off];
    __syncthreads();
  }
  int boff = red[0];
  int i = b * 256 + t;
  if (i < N) {
    rowptr[i] += boff;
    dinv[i] = rsqrtf((float)deg[i] + 1.0f);
  }
  if (i == 0) rowptr[N] = E;
}

// ---- common MFMA compute+store given A-fragments ----
__device__ __forceinline__ void mfma_compute_store(h8 af[2][4],
                                                   const _Float16* ws,
                                                   const float* __restrict__ dinv,
                                                   unsigned char* __restrict__ C,
                                                   int N, int rb, int lm, int q) {
  f4 acc[2][8];
#pragma unroll
  for (int mt = 0; mt < 2; ++mt)
#pragma unroll
    for (int ct = 0; ct < 8; ++ct)
      acc[mt][ct] = (f4){0.0f, 0.0f, 0.0f, 0.0f};

#pragma unroll
  for (int ct = 0; ct < 8; ++ct) {
    h8 bf[4];
#pragma unroll
    for (int kc = 0; kc < 4; ++kc)
      bf[kc] = *(const h8*)&ws[(ct * 16 + lm) * 136 + kc * 32 + q * 8];
#pragma unroll
    for (int mt = 0; mt < 2; ++mt)
#pragma unroll
      for (int kc = 0; kc < 4; ++kc)
        acc[mt][ct] = __builtin_amdgcn_mfma_f32_16x16x32_f16(af[mt][kc], bf[kc],
                                                             acc[mt][ct], 0, 0, 0);
  }

#pragma unroll
  for (int mt = 0; mt < 2; ++mt) {
#pragma unroll
    for (int r = 0; r < 4; ++r) {
      int row = rb + mt * 16 + q * 4 + r;
      if (row < N) {
        float dn = dinv[row];
        unsigned char* Cp = &C[(size_t)row * 128 + lm];
#pragma unroll
        for (int ct = 0; ct < 8; ++ct) {
          float v = acc[mt][ct][r] * dn;
          unsigned int p = __builtin_amdgcn_cvt_pk_fp8_f32(v, v, 0, false);
          Cp[ct * 16] = (unsigned char)(p & 0xFF);
        }
      }
    }
  }
}

__device__ __forceinline__ void stage_w(const _Float16* __restrict__ Wt,
                                        _Float16* ws, int tid) {
#pragma unroll
  for (int i = 0; i < 8; ++i) {
    int c0 = tid + i * 256;
    int r = c0 >> 4;
    int off = (c0 & 15) * 8;
    *(h8*)&ws[r * 136 + off] = *(const h8*)&Wt[r * 128 + off];
  }
  __syncthreads();
}

// ---- MFMA GEMM body, fp16 A (layers 2,3) ----
__device__ __forceinline__ void mfma_body(const _Float16* __restrict__ A,
                                          const _Float16* __restrict__ Wt,
                                          const float* __restrict__ dinv,
                                          unsigned char* __restrict__ C, int N,
                                          int bid, int tid, _Float16* ws) {
  stage_w(Wt, ws, tid);
  const int wv = tid >> 6, l = tid & 63;
  const int lm = l & 15, q = l >> 4;
  const int rb = bid * 128 + wv * 32;

  h8 af[2][4];
#pragma unroll
  for (int mt = 0; mt < 2; ++mt) {
    const _Float16* Ap = &A[(size_t)(rb + mt * 16 + lm) * 128];
#pragma unroll
    for (int kc = 0; kc < 4; ++kc)
      af[mt][kc] = *(const h8*)&Ap[kc * 32 + q * 8];
  }
  mfma_compute_store(af, ws, dinv, C, N, rb, lm, q);
}

// ---- MFMA GEMM body, fp32 A with in-register cvt (layer 1 reads x directly) ----
__device__ __forceinline__ void mfma_body32(const float* __restrict__ A,
                                            const _Float16* __restrict__ Wt,
                                            const float* __restrict__ dinv,
                                            unsigned char* __restrict__ C, int N,
                                            int bid, int tid, _Float16* ws) {
  stage_w(Wt, ws, tid);
  const int wv = tid >> 6, l = tid & 63;
  const int lm = l & 15, q = l >> 4;
  const int rb = bid * 128 + wv * 32;

  h8 af[2][4];
#pragma unroll
  for (int mt = 0; mt < 2; ++mt) {
    int row = rb + mt * 16 + lm;
    if (row < N) {
      const float* Ap = &A[(size_t)row * 128];
#pragma unroll
      for (int kc = 0; kc < 4; ++kc) {
        float4 v0 = *(const float4*)&Ap[kc * 32 + q * 8];
        float4 v1 = *(const float4*)&Ap[kc * 32 + q * 8 + 4];
        h8 a;
        a[0] = (_Float16)v0.x; a[1] = (_Float16)v0.y;
        a[2] = (_Float16)v0.z; a[3] = (_Float16)v0.w;
        a[4] = (_Float16)v1.x; a[5] = (_Float16)v1.y;
        a[6] = (_Float16)v1.z; a[7] = (_Float16)v1.w;
        af[mt][kc] = a;
      }
    } else {
#pragma unroll
      for (int kc = 0; kc < 4; ++kc) {
        h8 a;
#pragma unroll
        for (int j = 0; j < 8; ++j) a[j] = (_Float16)0.0f;
        af[mt][kc] = a;
      }
    }
  }
  mfma_compute_store(af, ws, dinv, C, N, rb, lm, q);
}

// ---- standalone MFMA GEMM (layers 2,3) ----
__global__ __launch_bounds__(256) void k_mfma(const _Float16* __restrict__ A,
                                              const _Float16* __restrict__ Wt,
                                              const float* __restrict__ dinv,
                                              unsigned char* __restrict__ C, int N) {
  __shared__ _Float16 ws[128 * 136];
  mfma_body(A, Wt, dinv, C, N, blockIdx.x, threadIdx.x, ws);
}

// ---- fused: blocks [0,nbg) do mfma layer-1 (fp32 A = x); rest do CSR fill ----
__global__ __launch_bounds__(256) void k_fill_mfma(const float* __restrict__ A32,
                                                   const _Float16* __restrict__ Wt,
                                                   const float* __restrict__ dinv,
                                                   unsigned char* __restrict__ C,
                                                   const int* __restrict__ ei,
                                                   const int* __restrict__ rowptr,
                                                   const int* __restrict__ rank,
                                                   int* __restrict__ col,
                                                   int N, int E, int nbg) {
  __shared__ _Float16 ws[128 * 136];
  if ((int)blockIdx.x < nbg) {
    mfma_body32(A32, Wt, dinv, C, N, blockIdx.x, threadIdx.x, ws);
  } else {
    int e = (blockIdx.x - nbg) * 256 + threadIdx.x;
    if (e < E) {
      int d = ei[E + e];
      col[rowptr[d] + rank[e]] = ei[e];
    }
  }
}

// ---- fused gather (fp8 table -> fp16 h): h[n] = relu(dinv[n]*(xws[n]+sum xws[src])+b)
// half-wave (32 lanes) per node, lane owns 4 cols (4B fp8x4 loads); 8 nodes/block.
__global__ __launch_bounds__(256) void k_gather(const int* __restrict__ rowptr,
                                                const int* __restrict__ col,
                                                const unsigned char* __restrict__ xf8,
                                                const float* __restrict__ dinv,
                                                const float* __restrict__ b,
                                                _Float16* __restrict__ h, int N) {
  int node = blockIdx.x * 8 + (threadIdx.x >> 5);
  if (node >= N) return;
  int sl = threadIdx.x & 31;
  int beg = rowptr[node], end = rowptr[node + 1];
  const unsigned int* xw = (const unsigned int*)xf8;   // row stride 32 uints

  float a0 = 0.0f, a1 = 0.0f, a2 = 0.0f, a3 = 0.0f;
  int e = beg;
  for (; e + 3 < end; e += 4) {
    int s0 = col[e], s1 = col[e + 1], s2 = col[e + 2], s3 = col[e + 3];
    unsigned int w0 = xw[(size_t)s0 * 32 + sl];
    unsigned int w1 = xw[(size_t)s1 * 32 + sl];
    unsigned int w2 = xw[(size_t)s2 * 32 + sl];
    unsigned int w3 = xw[(size_t)s3 * 32 + sl];
    f2 l0 = __builtin_amdgcn_cvt_pk_f32_fp8((int)w0, false);
    f2 h0 = __builtin_amdgcn_cvt_pk_f32_fp8((int)w0, true);
    f2 l1 = __builtin_amdgcn_cvt_pk_f32_fp8((int)w1, false);
    f2 h1 = __builtin_amdgcn_cvt_pk_f32_fp8((int)w1, true);
    f2 l2 = __builtin_amdgcn_cvt_pk_f32_fp8((int)w2, false);
    f2 h2 = __builtin_amdgcn_cvt_pk_f32_fp8((int)w2, true);
    f2 l3 = __builtin_amdgcn_cvt_pk_f32_fp8((int)w3, false);
    f2 h3 = __builtin_amdgcn_cvt_pk_f32_fp8((int)w3, true);
    a0 += (l0[0] + l1[0]) + (l2[0] + l3[0]);
    a1 += (l0[1] + l1[1]) + (l2[1] + l3[1]);
    a2 += (h0[0] + h1[0]) + (h2[0] + h3[0]);
    a3 += (h0[1] + h1[1]) + (h2[1] + h3[1]);
  }
  for (; e < end; ++e) {
    unsigned int w0 = xw[(size_t)col[e] * 32 + sl];
    f2 l0 = __builtin_amdgcn_cvt_pk_f32_fp8((int)w0, false);
    f2 h0 = __builtin_amdgcn_cvt_pk_f32_fp8((int)w0, true);
    a0 += l0[0]; a1 += l0[1]; a2 += h0[0]; a3 += h0[1];
  }
  float dn = dinv[node];
  unsigned int wsf = xw[(size_t)node * 32 + sl];
  f2 sl0 = __builtin_amdgcn_cvt_pk_f32_fp8((int)wsf, false);
  f2 sh0 = __builtin_amdgcn_cvt_pk_f32_fp8((int)wsf, true);
  int c = sl * 4;
  float4 bb = *(const float4*)&b[c];
  h4 o;
  o[0] = (_Float16)fmaxf(fmaf(dn, a0 + sl0[0], bb.x), 0.0f);
  o[1] = (_Float16)fmaxf(fmaf(dn, a1 + sl0[1], bb.y), 0.0f);
  o[2] = (_Float16)fmaxf(fmaf(dn, a2 + sh0[0], bb.z), 0.0f);
  o[3] = (_Float16)fmaxf(fmaf(dn, a3 + sh0[1], bb.w), 0.0f);
  *(h4*)&h[(size_t)node * 128 + c] = o;
}

// ---- segmented mean-pool (fp16 h): grid (NGRAPH, POOL_RS) ----
__global__ __launch_bounds__(256) void k_pool(const _Float16* __restrict__ h,
                                              const int* __restrict__ gstart,
                                              float* __restrict__ sums) {
  int g = blockIdx.x;
  int rs = blockIdx.y;
  int beg = gstart[g], end = gstart[g + 1];
  int tid = threadIdx.x;
  int ty = tid >> 5;
  int q = (tid & 31) * 4;

  float4 acc; acc.x = acc.y = acc.z = acc.w = 0.0f;
  for (int r = beg + rs * 8 + ty; r < end; r += POOL_RS * 8) {
    h4 v = *(const h4*)&h[(size_t)r * 128 + q];
    acc.x += (float)v[0]; acc.y += (float)v[1];
    acc.z += (float)v[2]; acc.w += (float)v[3];
  }
  __shared__ float s[8][128];
  *(float4*)&s[ty][q] = acc;
  __syncthreads();
  if (tid < 32) {
    int qq = tid * 4;
    float4 t; t.x = t.y = t.z = t.w = 0.0f;
#pragma unroll
    for (int j = 0; j < 8; ++j) {
      float4 v = *(float4*)&s[j][qq];
      t.x += v.x; t.y += v.y; t.z += v.z; t.w += v.w;
    }
    float* base = &sums[g * 128 + qq];
    unsafeAtomicAdd(base + 0, t.x);
    unsafeAtomicAdd(base + 1, t.y);
    unsafeAtomicAdd(base + 2, t.z);
    unsafeAtomicAdd(base + 3, t.w);
  }
}

// ---- head ----
__global__ __launch_bounds__(640) void k_head(const float* __restrict__ sums,
                                              const int* __restrict__ gstart,
                                              const float* __restrict__ Wc,
                                              const float* __restrict__ bc,
                                              float* __restrict__ out) {
  int t = threadIdx.x;
  int g = t / 10, c = t % 10;
  float cntf = (float)(gstart[g + 1] - gstart[g]);
  float inv = 1.0f / fmaxf(cntf, 1.0f);
  float acc = 0.0f;
  for (int h = 0; h < 128; ++h)
    acc = fmaf(sums[g * 128 + h], Wc[h * 10 + c], acc);
  out[t] = acc * inv + bc[c];
}

extern "C" void kernel_launch(void* const* d_in, const int* in_sizes, int n_in,
                              void* d_out, int out_size, void* d_ws, size_t ws_size,
                              hipStream_t stream) {
  const float* x   = (const float*)d_in[0];
  const int*   ei  = (const int*)d_in[1];
  const int*   bat = (const int*)d_in[2];
  const float* W1  = (const float*)d_in[3];
  const float* b1  = (const float*)d_in[4];
  const float* W2  = (const float*)d_in[5];
  const float* b2  = (const float*)d_in[6];
  const float* W3  = (const float*)d_in[7];
  const float* b3  = (const float*)d_in[8];
  const float* Wc  = (const float*)d_in[9];
  const float* bc  = (const float*)d_in[10];

  const int N = in_sizes[0] / 128;
  const int E = in_sizes[1] / 2;
  const int NP = ((N + 127) / 128) * 128;        // padded rows for fp16 buffers

  // workspace layout
  char* wsb = (char*)d_ws;
  int*   deg    = (int*)wsb;                      wsb += (size_t)N * 4;
  int*   rowptr = (int*)wsb;                      wsb += (size_t)(N + 1) * 4;
  int*   bsum   = (int*)wsb;                      wsb += 256 * 4;
  float* dinv   = (float*)wsb;                    wsb += (size_t)N * 4;
  int*   col    = (int*)wsb;                      wsb += (size_t)E * 4;
  int*   rank   = (int*)wsb;                      wsb += (size_t)E * 4;
  float* sums   = (float*)wsb;                    wsb += NGRAPH * HDIM * 4;
  int*   gstart = (int*)wsb;                      wsb += (NGRAPH + 1) * 4;
  wsb = (char*)(((size_t)wsb + 255) & ~(size_t)255);
  _Float16* Wt  = (_Float16*)wsb;                 wsb += 3 * 16384 * 2;
  wsb = (char*)(((size_t)wsb + 255) & ~(size_t)255);
  unsigned char* B1 = (unsigned char*)wsb;        wsb += (size_t)NP * 128;     // fp8 table
  wsb = (char*)(((size_t)wsb + 255) & ~(size_t)255);
  _Float16* B2  = (_Float16*)wsb;

  const int setup_elems = (N > 3 * 16384) ? N : 3 * 16384;
  const int nb_set = (setup_elems + 255) / 256;
  const int nb_N   = (N + 255) / 256;
  const int nb_E   = (E + 255) / 256;
  const int nb_gem = (N + 127) / 128;
  const int nb_gat = (N + 7) / 8;

  hipMemsetAsync(deg, 0, (size_t)N * 4, stream);
  k_setup_hist<<<nb_set + nb_E, 256, 0, stream>>>(bat, ei, W1, W2, W3,
                                                  Wt, deg, rank, sums, gstart,
                                                  N, E, nb_set);
  k_scan1<<<nb_N, 256, 0, stream>>>(deg, rowptr, bsum, N);
  k_scan23<<<nb_N, 256, 0, stream>>>(deg, rowptr, bsum, dinv, N, E);

  // layer 1 GEMM (fp32 A = x, in-register cvt) overlapped with atomic-free CSR fill
  k_fill_mfma<<<nb_gem + nb_E, 256, 0, stream>>>(x, Wt, dinv, B1,
                                                 ei, rowptr, rank, col, N, E, nb_gem);
  k_gather<<<nb_gat, 256, 0, stream>>>(rowptr, col, B1, dinv, b1, B2, N);

  k_mfma<<<nb_gem, 256, 0, stream>>>(B2, Wt + 16384, dinv, B1, N);
  k_gather<<<nb_gat, 256, 0, stream>>>(rowptr, col, B1, dinv, b2, B2, N);

  k_mfma<<<nb_gem, 256, 0, stream>>>(B2, Wt + 32768, dinv, B1, N);
  k_gather<<<nb_gat, 256, 0, stream>>>(rowptr, col, B1, dinv, b3, B2, N);

  dim3 pgrid(NGRAPH, POOL_RS);
  k_pool<<<pgrid, 256, 0, stream>>>(B2, gstart, sums);
  k_head<<<1, 640, 0, stream>>>(sums, gstart, Wc, bc, (float*)d_out);
}

// Round 15
// 264.883 us; speedup vs baseline: 3.9329x; 1.0017x over previous
//
#include <hip/hip_runtime.h>

#define NGRAPH 64
#define HDIM 128

typedef _Float16 h4 __attribute__((ext_vector_type(4)));
typedef _Float16 h8 __attribute__((ext_vector_type(8)));
typedef float    f4 __attribute__((ext_vector_type(4)));
typedef float    f2 __attribute__((ext_vector_type(2)));

// ---- fused setup + histogram: blocks [0,nb_set) do setup; [nb_set,..) do hist ----
// deg must be zeroed before this kernel (hipMemsetAsync).
__global__ __launch_bounds__(256) void k_setup_hist(const int* __restrict__ bat,
                                                    const int* __restrict__ ei,
                                                    const float* __restrict__ W1,
                                                    const float* __restrict__ W2,
                                                    const float* __restrict__ W3,
                                                    _Float16* __restrict__ Wt,
                                                    int* __restrict__ deg,
                                                    int* __restrict__ rank,
                                                    int* __restrict__ gstart,
                                                    int N, int E, int nb_set) {
  int c = blockIdx.x;
  if (c < nb_set) {
    int i = c * 256 + threadIdx.x;
    if (i < 3 * 16384) {                    // Wt[l][n][k] = fp16(W_l[k][n])
      int l = i >> 14, j = i & 16383;
      int k = j >> 7, n = j & 127;
      const float* W = (l == 0) ? W1 : (l == 1) ? W2 : W3;
      Wt[l * 16384 + n * 128 + k] = (_Float16)W[k * 128 + n];
    }
    if (i < N) {
      int b = bat[i];
      int prev = (i == 0) ? -1 : bat[i - 1];
      for (int g = prev + 1; g <= b; ++g) gstart[g] = i;
      if (i == N - 1)
        for (int g = b + 1; g <= NGRAPH; ++g) gstart[g] = N;
    }
  } else {
    int e = (c - nb_set) * 256 + threadIdx.x;
    if (e < E) rank[e] = atomicAdd(&deg[ei[E + e]], 1);
  }
}

// ---- scan pass 1: per-block exclusive scan of deg ----
__global__ __launch_bounds__(256) void k_scan1(const int* __restrict__ deg,
                                               int* __restrict__ rowptr,
                                               int* __restrict__ bsum, int N) {
  __shared__ int s[256];
  int tid = threadIdx.x;
  int i = blockIdx.x * 256 + tid;
  int v = (i < N) ? deg[i] : 0;
  s[tid] = v;
  __syncthreads();
#pragma unroll
  for (int off = 1; off < 256; off <<= 1) {
    int t = (tid >= off) ? s[tid - off] : 0;
    __syncthreads();
    s[tid] += t;
    __syncthreads();
  }
  if (i < N) rowptr[i] = s[tid] - v;       // block-local exclusive
  if (tid == 255) bsum[blockIdx.x] = s[255];
}

// ---- scan pass 2+3 fused: each block redundantly reduces bsum[0..b); dinv ----
__global__ __launch_bounds__(256) void k_scan23(const int* __restrict__ deg,
                                                int* __restrict__ rowptr,
                                                const int* __restrict__ bsum,
                                                float* __restrict__ dinv,
                                                int N, int E) {
  __shared__ int red[256];
  int b = blockIdx.x, t = threadIdx.x;
  int partial = 0;
  for (int j = t; j < b; j += 256) partial += bsum[j];
  red[t] = partial;
  __syncthreads();
#pragma unroll
  for (int off = 128; off > 0; off >>= 1) {
    if (t < off) red[t] += red[t + off];
    __syncthreads();
  }
  int boff = red[0];
  int i = b * 256 + t;
  if (i < N) {
    rowptr[i] += boff;
    dinv[i] = rsqrtf((float)deg[i] + 1.0f);
  }
  if (i == 0) rowptr[N] = E;
}

// ---- common MFMA compute+store given A-fragments ----
__device__ __forceinline__ void mfma_compute_store(h8 af[2][4],
                                                   const _Float16* ws,
                                                   const float* __restrict__ dinv,
                                                   unsigned char* __restrict__ C,
                                                   int N, int rb, int lm, int q) {
  f4 acc[2][8];
#pragma unroll
  for (int mt = 0; mt < 2; ++mt)
#pragma unroll
    for (int ct = 0; ct < 8; ++ct)
      acc[mt][ct] = (f4){0.0f, 0.0f, 0.0f, 0.0f};

#pragma unroll
  for (int ct = 0; ct < 8; ++ct) {
    h8 bf[4];
#pragma unroll
    for (int kc = 0; kc < 4; ++kc)
      bf[kc] = *(const h8*)&ws[(ct * 16 + lm) * 136 + kc * 32 + q * 8];
#pragma unroll
    for (int mt = 0; mt < 2; ++mt)
#pragma unroll
      for (int kc = 0; kc < 4; ++kc)
        acc[mt][ct] = __builtin_amdgcn_mfma_f32_16x16x32_f16(af[mt][kc], bf[kc],
                                                             acc[mt][ct], 0, 0, 0);
  }

#pragma unroll
  for (int mt = 0; mt < 2; ++mt) {
#pragma unroll
    for (int r = 0; r < 4; ++r) {
      int row = rb + mt * 16 + q * 4 + r;
      if (row < N) {
        float dn = dinv[row];
        unsigned char* Cp = &C[(size_t)row * 128 + lm];
#pragma unroll
        for (int ct = 0; ct < 8; ++ct) {
          float v = acc[mt][ct][r] * dn;
          unsigned int p = __builtin_amdgcn_cvt_pk_fp8_f32(v, v, 0, false);
          Cp[ct * 16] = (unsigned char)(p & 0xFF);
        }
      }
    }
  }
}

__device__ __forceinline__ void stage_w(const _Float16* __restrict__ Wt,
                                        _Float16* ws, int tid) {
#pragma unroll
  for (int i = 0; i < 8; ++i) {
    int c0 = tid + i * 256;
    int r = c0 >> 4;
    int off = (c0 & 15) * 8;
    *(h8*)&ws[r * 136 + off] = *(const h8*)&Wt[r * 128 + off];
  }
  __syncthreads();
}

// ---- MFMA GEMM body, fp16 A (layers 2,3) ----
__device__ __forceinline__ void mfma_body(const _Float16* __restrict__ A,
                                          const _Float16* __restrict__ Wt,
                                          const float* __restrict__ dinv,
                                          unsigned char* __restrict__ C, int N,
                                          int bid, int tid, _Float16* ws) {
  stage_w(Wt, ws, tid);
  const int wv = tid >> 6, l = tid & 63;
  const int lm = l & 15, q = l >> 4;
  const int rb = bid * 128 + wv * 32;

  h8 af[2][4];
#pragma unroll
  for (int mt = 0; mt < 2; ++mt) {
    const _Float16* Ap = &A[(size_t)(rb + mt * 16 + lm) * 128];
#pragma unroll
    for (int kc = 0; kc < 4; ++kc)
      af[mt][kc] = *(const h8*)&Ap[kc * 32 + q * 8];
  }
  mfma_compute_store(af, ws, dinv, C, N, rb, lm, q);
}

// ---- MFMA GEMM body, fp32 A with in-register cvt (layer 1 reads x directly) ----
__device__ __forceinline__ void mfma_body32(const float* __restrict__ A,
                                            const _Float16* __restrict__ Wt,
                                            const float* __restrict__ dinv,
                                            unsigned char* __restrict__ C, int N,
                                            int bid, int tid, _Float16* ws) {
  stage_w(Wt, ws, tid);
  const int wv = tid >> 6, l = tid & 63;
  const int lm = l & 15, q = l >> 4;
  const int rb = bid * 128 + wv * 32;

  h8 af[2][4];
#pragma unroll
  for (int mt = 0; mt < 2; ++mt) {
    int row = rb + mt * 16 + lm;
    if (row < N) {
      const float* Ap = &A[(size_t)row * 128];
#pragma unroll
      for (int kc = 0; kc < 4; ++kc) {
        float4 v0 = *(const float4*)&Ap[kc * 32 + q * 8];
        float4 v1 = *(const float4*)&Ap[kc * 32 + q * 8 + 4];
        h8 a;
        a[0] = (_Float16)v0.x; a[1] = (_Float16)v0.y;
        a[2] = (_Float16)v0.z; a[3] = (_Float16)v0.w;
        a[4] = (_Float16)v1.x; a[5] = (_Float16)v1.y;
        a[6] = (_Float16)v1.z; a[7] = (_Float16)v1.w;
        af[mt][kc] = a;
      }
    } else {
#pragma unroll
      for (int kc = 0; kc < 4; ++kc) {
        h8 a;
#pragma unroll
        for (int j = 0; j < 8; ++j) a[j] = (_Float16)0.0f;
        af[mt][kc] = a;
      }
    }
  }
  mfma_compute_store(af, ws, dinv, C, N, rb, lm, q);
}

// ---- standalone MFMA GEMM (layers 2,3) ----
__global__ __launch_bounds__(256) void k_mfma(const _Float16* __restrict__ A,
                                              const _Float16* __restrict__ Wt,
                                              const float* __restrict__ dinv,
                                              unsigned char* __restrict__ C, int N) {
  __shared__ _Float16 ws[128 * 136];
  mfma_body(A, Wt, dinv, C, N, blockIdx.x, threadIdx.x, ws);
}

// ---- fused: blocks [0,nbg) do mfma layer-1 (fp32 A = x); rest do CSR fill ----
__global__ __launch_bounds__(256) void k_fill_mfma(const float* __restrict__ A32,
                                                   const _Float16* __restrict__ Wt,
                                                   const float* __restrict__ dinv,
                                                   unsigned char* __restrict__ C,
                                                   const int* __restrict__ ei,
                                                   const int* __restrict__ rowptr,
                                                   const int* __restrict__ rank,
                                                   int* __restrict__ col,
                                                   int N, int E, int nbg) {
  __shared__ _Float16 ws[128 * 136];
  if ((int)blockIdx.x < nbg) {
    mfma_body32(A32, Wt, dinv, C, N, blockIdx.x, threadIdx.x, ws);
  } else {
    int e = (blockIdx.x - nbg) * 256 + threadIdx.x;
    if (e < E) {
      int d = ei[E + e];
      col[rowptr[d] + rank[e]] = ei[e];
    }
  }
}

// ---- fused gather (fp8 table -> fp16 h): h[n] = relu(dinv[n]*(xws[n]+sum xws[src])+b)
// 16 lanes per node, lane owns 8 cols (8B uint2 loads); 16 nodes/block.
__global__ __launch_bounds__(256) void k_gather(const int* __restrict__ rowptr,
                                                const int* __restrict__ col,
                                                const unsigned char* __restrict__ xf8,
                                                const float* __restrict__ dinv,
                                                const float* __restrict__ b,
                                                _Float16* __restrict__ h, int N) {
  int node = blockIdx.x * 16 + (threadIdx.x >> 4);
  if (node >= N) return;
  int sl = threadIdx.x & 15;               // lane within node group
  int beg = rowptr[node], end = rowptr[node + 1];
  const uint2* xw = (const uint2*)xf8;     // row stride 16 uint2

  float a0 = 0, a1 = 0, a2 = 0, a3 = 0, a4 = 0, a5 = 0, a6 = 0, a7 = 0;
  int e = beg;
  for (; e + 3 < end; e += 4) {
    int s0 = col[e], s1 = col[e + 1], s2 = col[e + 2], s3 = col[e + 3];
    uint2 w0 = xw[(size_t)s0 * 16 + sl];
    uint2 w1 = xw[(size_t)s1 * 16 + sl];
    uint2 w2 = xw[(size_t)s2 * 16 + sl];
    uint2 w3 = xw[(size_t)s3 * 16 + sl];
#pragma unroll
    for (int j = 0; j < 4; ++j) {
      uint2 w = (j == 0) ? w0 : (j == 1) ? w1 : (j == 2) ? w2 : w3;
      f2 lx = __builtin_amdgcn_cvt_pk_f32_fp8((int)w.x, false);
      f2 hx = __builtin_amdgcn_cvt_pk_f32_fp8((int)w.x, true);
      f2 ly = __builtin_amdgcn_cvt_pk_f32_fp8((int)w.y, false);
      f2 hy = __builtin_amdgcn_cvt_pk_f32_fp8((int)w.y, true);
      a0 += lx[0]; a1 += lx[1]; a2 += hx[0]; a3 += hx[1];
      a4 += ly[0]; a5 += ly[1]; a6 += hy[0]; a7 += hy[1];
    }
  }
  for (; e < end; ++e) {
    uint2 w = xw[(size_t)col[e] * 16 + sl];
    f2 lx = __builtin_amdgcn_cvt_pk_f32_fp8((int)w.x, false);
    f2 hx = __builtin_amdgcn_cvt_pk_f32_fp8((int)w.x, true);
    f2 ly = __builtin_amdgcn_cvt_pk_f32_fp8((int)w.y, false);
    f2 hy = __builtin_amdgcn_cvt_pk_f32_fp8((int)w.y, true);
    a0 += lx[0]; a1 += lx[1]; a2 += hx[0]; a3 += hx[1];
    a4 += ly[0]; a5 += ly[1]; a6 += hy[0]; a7 += hy[1];
  }
  float dn = dinv[node];
  uint2 wsf = xw[(size_t)node * 16 + sl];
  f2 slx = __builtin_amdgcn_cvt_pk_f32_fp8((int)wsf.x, false);
  f2 shx = __builtin_amdgcn_cvt_pk_f32_fp8((int)wsf.x, true);
  f2 sly = __builtin_amdgcn_cvt_pk_f32_fp8((int)wsf.y, false);
  f2 shy = __builtin_amdgcn_cvt_pk_f32_fp8((int)wsf.y, true);
  int c = sl * 8;
  float4 b0 = *(const float4*)&b[c];
  float4 b1v = *(const float4*)&b[c + 4];
  h8 o;
  o[0] = (_Float16)fmaxf(fmaf(dn, a0 + slx[0], b0.x), 0.0f);
  o[1] = (_Float16)fmaxf(fmaf(dn, a1 + slx[1], b0.y), 0.0f);
  o[2] = (_Float16)fmaxf(fmaf(dn, a2 + shx[0], b0.z), 0.0f);
  o[3] = (_Float16)fmaxf(fmaf(dn, a3 + shx[1], b0.w), 0.0f);
  o[4] = (_Float16)fmaxf(fmaf(dn, a4 + sly[0], b1v.x), 0.0f);
  o[5] = (_Float16)fmaxf(fmaf(dn, a5 + sly[1], b1v.y), 0.0f);
  o[6] = (_Float16)fmaxf(fmaf(dn, a6 + shy[0], b1v.z), 0.0f);
  o[7] = (_Float16)fmaxf(fmaf(dn, a7 + shy[1], b1v.w), 0.0f);
  *(h8*)&h[(size_t)node * 128 + c] = o;
}

// ---- fused pool + head: one block per graph, no atomics ----
__global__ __launch_bounds__(256) void k_poolhead(const _Float16* __restrict__ h,
                                                  const int* __restrict__ gstart,
                                                  const float* __restrict__ Wc,
                                                  const float* __restrict__ bc,
                                                  float* __restrict__ out) {
  int g = blockIdx.x;
  int beg = gstart[g], end = gstart[g + 1];
  int tid = threadIdx.x;
  int ty = tid >> 5;            // 8 row groups
  int q = (tid & 31) * 4;       // col quad

  float4 acc; acc.x = acc.y = acc.z = acc.w = 0.0f;
  for (int r = beg + ty; r < end; r += 8) {
    h4 v = *(const h4*)&h[(size_t)r * 128 + q];
    acc.x += (float)v[0]; acc.y += (float)v[1];
    acc.z += (float)v[2]; acc.w += (float)v[3];
  }
  __shared__ float s[8][128];
  *(float4*)&s[ty][q] = acc;
  __syncthreads();
  if (tid < 32) {
    int qq = tid * 4;
    float4 t; t.x = t.y = t.z = t.w = 0.0f;
#pragma unroll
    for (int j = 0; j < 8; ++j) {
      float4 v = *(float4*)&s[j][qq];
      t.x += v.x; t.y += v.y; t.z += v.z; t.w += v.w;
    }
    *(float4*)&s[0][qq] = t;
  }
  __syncthreads();
  if (tid < 10) {
    float cntf = (float)(end - beg);
    float inv = 1.0f / fmaxf(cntf, 1.0f);
    float a = 0.0f;
    for (int hh = 0; hh < 128; ++hh)
      a = fmaf(s[0][hh], Wc[hh * 10 + tid], a);
    out[g * 10 + tid] = a * inv + bc[tid];
  }
}

extern "C" void kernel_launch(void* const* d_in, const int* in_sizes, int n_in,
                              void* d_out, int out_size, void* d_ws, size_t ws_size,
                              hipStream_t stream) {
  const float* x   = (const float*)d_in[0];
  const int*   ei  = (const int*)d_in[1];
  const int*   bat = (const int*)d_in[2];
  const float* W1  = (const float*)d_in[3];
  const float* b1  = (const float*)d_in[4];
  const float* W2  = (const float*)d_in[5];
  const float* b2  = (const float*)d_in[6];
  const float* W3  = (const float*)d_in[7];
  const float* b3  = (const float*)d_in[8];
  const float* Wc  = (const float*)d_in[9];
  const float* bc  = (const float*)d_in[10];

  const int N = in_sizes[0] / 128;
  const int E = in_sizes[1] / 2;
  const int NP = ((N + 127) / 128) * 128;        // padded rows

  // workspace layout
  char* wsb = (char*)d_ws;
  int*   deg    = (int*)wsb;                      wsb += (size_t)N * 4;
  int*   rowptr = (int*)wsb;                      wsb += (size_t)(N + 1) * 4;
  int*   bsum   = (int*)wsb;                      wsb += 256 * 4;
  float* dinv   = (float*)wsb;                    wsb += (size_t)N * 4;
  int*   col    = (int*)wsb;                      wsb += (size_t)E * 4;
  int*   rank   = (int*)wsb;                      wsb += (size_t)E * 4;
  int*   gstart = (int*)wsb;                      wsb += (NGRAPH + 1) * 4;
  wsb = (char*)(((size_t)wsb + 255) & ~(size_t)255);
  _Float16* Wt  = (_Float16*)wsb;                 wsb += 3 * 16384 * 2;
  wsb = (char*)(((size_t)wsb + 255) & ~(size_t)255);
  unsigned char* B1 = (unsigned char*)wsb;        wsb += (size_t)NP * 128;     // fp8 table
  wsb = (char*)(((size_t)wsb + 255) & ~(size_t)255);
  _Float16* B2  = (_Float16*)wsb;

  const int setup_elems = (N > 3 * 16384) ? N : 3 * 16384;
  const int nb_set = (setup_elems + 255) / 256;
  const int nb_N   = (N + 255) / 256;
  const int nb_E   = (E + 255) / 256;
  const int nb_gem = (N + 127) / 128;
  const int nb_gat = (N + 15) / 16;

  hipMemsetAsync(deg, 0, (size_t)N * 4, stream);
  k_setup_hist<<<nb_set + nb_E, 256, 0, stream>>>(bat, ei, W1, W2, W3,
                                                  Wt, deg, rank, gstart,
                                                  N, E, nb_set);
  k_scan1<<<nb_N, 256, 0, stream>>>(deg, rowptr, bsum, N);
  k_scan23<<<nb_N, 256, 0, stream>>>(deg, rowptr, bsum, dinv, N, E);

  // layer 1 GEMM (fp32 A = x, in-register cvt) overlapped with atomic-free CSR fill
  k_fill_mfma<<<nb_gem + nb_E, 256, 0, stream>>>(x, Wt, dinv, B1,
                                                 ei, rowptr, rank, col, N, E, nb_gem);
  k_gather<<<nb_gat, 256, 0, stream>>>(rowptr, col, B1, dinv, b1, B2, N);

  k_mfma<<<nb_gem, 256, 0, stream>>>(B2, Wt + 16384, dinv, B1, N);
  k_gather<<<nb_gat, 256, 0, stream>>>(rowptr, col, B1, dinv, b2, B2, N);

  k_mfma<<<nb_gem, 256, 0, stream>>>(B2, Wt + 32768, dinv, B1, N);
  k_gather<<<nb_gat, 256, 0, stream>>>(rowptr, col, B1, dinv, b3, B2, N);

  k_poolhead<<<NGRAPH, 256, 0, stream>>>(B2, gstart, Wc, bc, (float*)d_out);
}